// Round 1
// baseline (125.126 us; speedup 1.0000x reference)
//
#include <hip/hip_runtime.h>
#include <cmath>

#define BB 256
#define TT 16
#define SS 32
#define DD 768
#define LROW 260   // padded LDS row stride (floats) for stage1 tiles

// ---------------------------------------------------------------------------
// stage1: per-batch-row i
//   sim[t][s] = ls * <vl[i,t,:], tl[i,s,:]>   (16x32x768 mini-GEMM, LDS-tiled)
//   tw = softmax_t(max_s sim)
//   vw[i,:]  = sum_t tw[t]*vl[i,t,:]
//   tbar[i,:] = mean_s tl[i,s,:]
// 256 threads: tid = slice(16) * 16 + tpos(4) * 4 + spos(4)
//   each thread: 4t x 8s output tile, over a 16-wide d-slice per 256-chunk.
// ---------------------------------------------------------------------------
__global__ __launch_bounds__(256) void hl_stage1(
    const float* __restrict__ vl, const float* __restrict__ tl,
    const float* __restrict__ temp,
    float* __restrict__ vw_ws, float* __restrict__ tb_ws)
{
    __shared__ float smem[12480];   // 48 rows * 260 = staging; aliased later
    const int i   = blockIdx.x;
    const int tid = threadIdx.x;
    const float lsc = expf(temp[0]);

    const int slice = tid >> 4;        // 0..15 (d-slice within chunk)
    const int tpos  = (tid >> 2) & 3;  // t base = tpos*4
    const int spos  = tid & 3;         // s base = spos*8

    const float* vli = vl + (size_t)i * TT * DD;
    const float* tli = tl + (size_t)i * SS * DD;

    float acc[4][8];
#pragma unroll
    for (int a0 = 0; a0 < 4; ++a0)
#pragma unroll
        for (int b0 = 0; b0 < 8; ++b0) acc[a0][b0] = 0.f;

    for (int c = 0; c < 3; ++c) {
        const int d0 = c << 8;  // chunk base in D
        // stage vl chunk: 16x256 floats, coalesced float4
#pragma unroll
        for (int k = 0; k < 4; ++k) {
            int f4 = tid + (k << 8);
            int r  = f4 >> 6;
            int dc = (f4 << 2) & 255;
            *(float4*)&smem[r * LROW + dc] =
                *(const float4*)&vli[r * DD + d0 + dc];
        }
        // stage tl chunk: 32x256 floats
#pragma unroll
        for (int k = 0; k < 8; ++k) {
            int f4 = tid + (k << 8);
            int r  = f4 >> 6;
            int dc = (f4 << 2) & 255;
            *(float4*)&smem[(16 + r) * LROW + dc] =
                *(const float4*)&tli[r * DD + d0 + dc];
        }
        __syncthreads();
#pragma unroll
        for (int step = 0; step < 4; ++step) {
            const int db = (slice << 4) + (step << 2);
            float4 av[4];
            float4 bv[8];
#pragma unroll
            for (int ti = 0; ti < 4; ++ti)
                av[ti] = *(const float4*)&smem[(tpos * 4 + ti) * LROW + db];
#pragma unroll
            for (int sj = 0; sj < 8; ++sj)
                bv[sj] = *(const float4*)&smem[(16 + spos * 8 + sj) * LROW + db];
#pragma unroll
            for (int ti = 0; ti < 4; ++ti)
#pragma unroll
                for (int sj = 0; sj < 8; ++sj)
                    acc[ti][sj] += av[ti].x * bv[sj].x + av[ti].y * bv[sj].y
                                 + av[ti].z * bv[sj].z + av[ti].w * bv[sj].w;
        }
        __syncthreads();
    }

    // split-D reduction over 16 slices (alias staging region, post-barrier)
#pragma unroll
    for (int ti = 0; ti < 4; ++ti)
#pragma unroll
        for (int sj = 0; sj < 8; ++sj) {
            int t = tpos * 4 + ti, s = spos * 8 + sj;
            smem[(t * 32 + s) * 16 + slice] = acc[ti][sj];
        }
    __syncthreads();
    for (int rep = 0; rep < 2; ++rep) {
        int o = tid + (rep << 8);
        float ssum = 0.f;
#pragma unroll
        for (int k = 0; k < 16; ++k) ssum += smem[o * 16 + k];
        smem[8192 + o] = lsc * ssum;     // scaled sim[t*32+s]
    }
    __syncthreads();
    if (tid < 16) {                       // rowmax over s
        float m = -3.0e38f;
        for (int s = 0; s < 32; ++s) m = fmaxf(m, smem[8192 + tid * 32 + s]);
        smem[8704 + tid] = m;
    }
    __syncthreads();
    if (tid == 0) {                       // tw = softmax over 16 t (tiny, serial)
        float M = -3.0e38f;
        for (int t = 0; t < 16; ++t) M = fmaxf(M, smem[8704 + t]);
        float ssum = 0.f;
        for (int t = 0; t < 16; ++t) {
            float e = expf(smem[8704 + t] - M);
            smem[8720 + t] = e;
            ssum += e;
        }
        float inv = 1.0f / ssum;
        for (int t = 0; t < 16; ++t) smem[8720 + t] *= inv;
    }
    __syncthreads();

    // vw and tbar: 3 d-columns per thread, coalesced, L2-hot re-read
#pragma unroll
    for (int k = 0; k < 3; ++k) {
        int d = tid + (k << 8);
        float vwv = 0.f;
#pragma unroll
        for (int t = 0; t < 16; ++t) vwv += smem[8720 + t] * vli[t * DD + d];
        vw_ws[(size_t)i * DD + d] = vwv;
        float tbv = 0.f;
#pragma unroll
        for (int s = 0; s < 32; ++s) tbv += tli[s * DD + d];
        tb_ws[(size_t)i * DD + d] = tbv * (1.0f / 32.0f);
    }
}

// ---------------------------------------------------------------------------
// stage2: 192 blocks = 3 modes x 64 blocks x 4 rows each.
//   mode 0: x[j] = ls*<vw[i], tbar[j]>  -> loss_local rows   (w = 0.4/B)
//   mode 1: x[j] = ls*<vg[i], tg[j]>    -> v2t rows          (w = 0.3/B)
//   mode 2: x[j] = ls*<tg[i], vg[j]>    -> t2v (cols of gs)  (w = 0.3/B)
// per row: loss_i = LSE_j(x) - x[i]; atomicAdd(out, w*loss_i)
// ---------------------------------------------------------------------------
__global__ __launch_bounds__(256) void hl_stage2(
    const float* __restrict__ vg, const float* __restrict__ tg,
    const float* __restrict__ vw, const float* __restrict__ tb,
    const float* __restrict__ temp, float* __restrict__ out)
{
    __shared__ float a_s[4 * DD];    // 4 staged A-rows
    __shared__ float xs[4 * 256];    // per-row logits
    __shared__ float wred[4];        // per-wave reduction partials
    __shared__ float bcast;

    const int tid  = threadIdx.x;
    const int mode = blockIdx.x >> 6;
    const int ib   = (blockIdx.x & 63) << 2;   // first of 4 rows
    const float lsc = expf(temp[0]);

    const float* Arows;
    const float* Mat;
    float w;
    if (mode == 0)      { Arows = vw + (size_t)ib * DD; Mat = tb; w = 0.4f / 256.0f; }
    else if (mode == 1) { Arows = vg + (size_t)ib * DD; Mat = tg; w = 0.3f / 256.0f; }
    else                { Arows = tg + (size_t)ib * DD; Mat = vg; w = 0.3f / 256.0f; }

#pragma unroll
    for (int k = 0; k < 3; ++k) {
        int f4 = tid + (k << 8);
        *(float4*)&a_s[f4 << 2] = *(const float4*)&Arows[f4 << 2];
    }
    __syncthreads();

    const float4* mrow = (const float4*)(Mat + (size_t)tid * DD);
    float4 acc[4];
#pragma unroll
    for (int r = 0; r < 4; ++r) { acc[r].x = acc[r].y = acc[r].z = acc[r].w = 0.f; }

#pragma unroll 4
    for (int k = 0; k < DD / 4; ++k) {
        float4 m4 = mrow[k];
#pragma unroll
        for (int r = 0; r < 4; ++r) {
            float4 a4 = *(const float4*)&a_s[r * DD + (k << 2)];
            acc[r].x += m4.x * a4.x;
            acc[r].y += m4.y * a4.y;
            acc[r].z += m4.z * a4.z;
            acc[r].w += m4.w * a4.w;
        }
    }
#pragma unroll
    for (int r = 0; r < 4; ++r)
        xs[r * 256 + tid] = (acc[r].x + acc[r].y + acc[r].z + acc[r].w) * lsc;
    __syncthreads();

    float local = 0.f;
    for (int r = 0; r < 4; ++r) {
        float v = xs[r * 256 + tid];
        // block max
        float m = v;
#pragma unroll
        for (int off = 32; off > 0; off >>= 1)
            m = fmaxf(m, __shfl_down(m, off, 64));
        if ((tid & 63) == 0) wred[tid >> 6] = m;
        __syncthreads();
        if (tid == 0)
            bcast = fmaxf(fmaxf(wred[0], wred[1]), fmaxf(wred[2], wred[3]));
        __syncthreads();
        float M = bcast;
        // block sum of exp
        float e = expf(v - M);
        float ssum = e;
#pragma unroll
        for (int off = 32; off > 0; off >>= 1)
            ssum += __shfl_down(ssum, off, 64);
        if ((tid & 63) == 0) wred[tid >> 6] = ssum;
        __syncthreads();
        if (tid == 0) {
            float Stot = wred[0] + wred[1] + wred[2] + wred[3];
            float lse  = M + logf(Stot);
            local += w * (lse - xs[r * 256 + ib + r]);
        }
        __syncthreads();   // protect wred before next iteration
    }
    if (tid == 0) atomicAdd(out, local);
}

extern "C" void kernel_launch(void* const* d_in, const int* in_sizes, int n_in,
                              void* d_out, int out_size, void* d_ws, size_t ws_size,
                              hipStream_t stream)
{
    const float* vg   = (const float*)d_in[0];  // video_global [256,768]
    const float* tg   = (const float*)d_in[1];  // text_global  [256,768]
    const float* vl   = (const float*)d_in[2];  // video_local  [256,16,768]
    const float* tl   = (const float*)d_in[3];  // text_local   [256,32,768]
    const float* temp = (const float*)d_in[4];  // [1]
    float* out = (float*)d_out;

    float* vw = (float*)d_ws;            // [256,768] tw-weighted video_local
    float* tb = vw + (size_t)BB * DD;    // [256,768] mean_s text_local

    hipMemsetAsync(out, 0, sizeof(float) * out_size, stream);
    hl_stage1<<<dim3(BB), dim3(256), 0, stream>>>(vl, tl, temp, vw, tb);
    hl_stage2<<<dim3(192), dim3(256), 0, stream>>>(vg, tg, vw, tb, temp, out);
}

// Round 2
// 117.971 us; speedup vs baseline: 1.0607x; 1.0607x over previous
//
#include <hip/hip_runtime.h>
#include <cmath>

#define BB 256
#define TT 16
#define SS 32
#define DD 768
#define LROW 260   // LDS staging row stride (floats), 16B-aligned

// ---------------------------------------------------------------------------
// stage1: per batch row i (256 blocks x 512 threads = 8 waves/CU)
//   sim[t][s] = ls*<vl[i,t,:], tl[i,s,:]>; tw = softmax_t(max_s sim)
//   vw[i,:] = sum_t tw[t]*vl[i,t,:];  tb[i,:] = mean_s tl[i,s,:]
// thread: slice = tid&15 (d-offset, lane-major => conflict-free LDS reads),
//         g = tid>>4: tg = g>>3 (4 t-rows), sg = g&7 (4 s-rows); acc[4][4].
// ---------------------------------------------------------------------------
__global__ __launch_bounds__(512) void hl_stage1(
    const float* __restrict__ vl, const float* __restrict__ tl,
    const float* __restrict__ temp,
    float* __restrict__ vw_ws, float* __restrict__ tb_ws)
{
    __shared__ float smem[12480];   // 48 x 260 staging; aliased as 512x17 transpose
    __shared__ float simb[512];
    __shared__ float rmax[16];
    __shared__ float twb[16];

    const int i   = blockIdx.x;
    const int tid = threadIdx.x;
    const float lsc = expf(temp[0]);

    const int slice = tid & 15;   // d sub-offset: 16 lanes x 16B = 256B contiguous
    const int g     = tid >> 4;   // 0..31
    const int tg    = g >> 3;     // 0..3  -> t rows tg*4..+4
    const int sg    = g & 7;      // 0..7  -> s rows sg*4..+4

    const float* vli = vl + (size_t)i * TT * DD;
    const float* tli = tl + (size_t)i * SS * DD;

    float acc[4][4];
#pragma unroll
    for (int a = 0; a < 4; ++a)
#pragma unroll
        for (int b = 0; b < 4; ++b) acc[a][b] = 0.f;

    for (int c = 0; c < 3; ++c) {
        const int d0 = c << 8;
        // stage vl chunk 16x256 (1024 float4, 2 per thread), coalesced
#pragma unroll
        for (int k = 0; k < 2; ++k) {
            int f4 = tid + (k << 9);
            int r  = f4 >> 6;
            int dc = (f4 & 63) << 2;
            *(float4*)&smem[r * LROW + dc] = *(const float4*)&vli[r * DD + d0 + dc];
        }
        // stage tl chunk 32x256 (2048 float4, 4 per thread)
#pragma unroll
        for (int k = 0; k < 4; ++k) {
            int f4 = tid + (k << 9);
            int r  = f4 >> 6;
            int dc = (f4 & 63) << 2;
            *(float4*)&smem[(16 + r) * LROW + dc] = *(const float4*)&tli[r * DD + d0 + dc];
        }
        __syncthreads();
#pragma unroll
        for (int step = 0; step < 4; ++step) {
            const int db = (slice << 4) + (step << 2);
            float4 av[4], bv[4];
#pragma unroll
            for (int ti = 0; ti < 4; ++ti)
                av[ti] = *(const float4*)&smem[(tg * 4 + ti) * LROW + db];
#pragma unroll
            for (int sj = 0; sj < 4; ++sj)
                bv[sj] = *(const float4*)&smem[(16 + sg * 4 + sj) * LROW + db];
#pragma unroll
            for (int ti = 0; ti < 4; ++ti)
#pragma unroll
                for (int sj = 0; sj < 4; ++sj)
                    acc[ti][sj] += av[ti].x * bv[sj].x + av[ti].y * bv[sj].y
                                 + av[ti].z * bv[sj].z + av[ti].w * bv[sj].w;
        }
        __syncthreads();
    }

    // split-D transpose (alias staging region): [pair][slice], pad 17
#pragma unroll
    for (int ti = 0; ti < 4; ++ti)
#pragma unroll
        for (int sj = 0; sj < 4; ++sj) {
            int t = tg * 4 + ti, s = sg * 4 + sj;
            smem[(t * 32 + s) * 17 + slice] = acc[ti][sj];
        }
    __syncthreads();
    {   // pair `tid` reduce over 16 slices
        float ssum = 0.f;
#pragma unroll
        for (int k = 0; k < 16; ++k) ssum += smem[tid * 17 + k];
        simb[tid] = lsc * ssum;
    }
    __syncthreads();
    if (tid < 16) {               // rowmax over s (rotated to avoid bank clash)
        float m = -3.0e38f;
        for (int s = 0; s < 32; ++s)
            m = fmaxf(m, simb[tid * 32 + ((s + tid) & 31)]);
        rmax[tid] = m;
    }
    __syncthreads();
    if (tid == 0) {               // tw = softmax over 16 t values
        float M = -3.0e38f;
        for (int t = 0; t < 16; ++t) M = fmaxf(M, rmax[t]);
        float ssum = 0.f;
        for (int t = 0; t < 16; ++t) {
            float e = expf(rmax[t] - M);
            twb[t] = e;
            ssum += e;
        }
        float inv = 1.0f / ssum;
        for (int t = 0; t < 16; ++t) twb[t] *= inv;
    }
    __syncthreads();

    // vw / tb tails: coalesced, L2-hot re-read
    for (int d = tid; d < DD; d += 512) {
        float vwv = 0.f;
#pragma unroll
        for (int t = 0; t < 16; ++t) vwv += twb[t] * vli[t * DD + d];
        vw_ws[(size_t)i * DD + d] = vwv;
        float tbv = 0.f;
#pragma unroll
        for (int s = 0; s < 32; ++s) tbv += tli[s * DD + d];
        tb_ws[(size_t)i * DD + d] = tbv * (1.0f / 32.0f);
    }
}

// ---------------------------------------------------------------------------
// hl_gemm: 256 blocks = mat(2) x ti(4) x tj(4) x p(8 K-splits of 96)
//   mat 0: G = ls*vg@tg^T  -> cparts[p][1] and transposed into cparts[p][2]
//   mat 1: L = ls*vw@tb^T  -> cparts[p][0]
// 64x64 tile, LDS-staged (As/Bs k-major), 4x4 register tile per thread.
// ---------------------------------------------------------------------------
__global__ __launch_bounds__(256) void hl_gemm(
    const float* __restrict__ vg, const float* __restrict__ tg,
    const float* __restrict__ vw, const float* __restrict__ tb,
    const float* __restrict__ temp, float* __restrict__ cparts)
{
    __shared__ float As[16][68];
    __shared__ float Bs[16][68];
    __shared__ float Tb[64][68];

    const int b   = blockIdx.x;
    const int p   = b & 7;
    const int tj  = (b >> 3) & 3;
    const int ti  = (b >> 5) & 3;
    const int mat = b >> 7;
    const int tid = threadIdx.x;
    const float lsc = expf(temp[0]);

    const float* A  = mat ? vw : vg;
    const float* Bm = mat ? tb : tg;
    const int i0 = ti * 64, j0 = tj * 64, kb0 = p * 96;

    const int srow = tid >> 2, skq = tid & 3;   // staging: row, k-quad
    const int tr = tid >> 4, tc = tid & 15;     // compute: 4 rows, 4 cols each

    float acc[4][4];
#pragma unroll
    for (int r = 0; r < 4; ++r)
#pragma unroll
        for (int cc = 0; cc < 4; ++cc) acc[r][cc] = 0.f;

    for (int ch = 0; ch < 6; ++ch) {
        const int kb = kb0 + ch * 16;
        float4 a4 = *(const float4*)&A [(size_t)(i0 + srow) * DD + kb + skq * 4];
        float4 b4 = *(const float4*)&Bm[(size_t)(j0 + srow) * DD + kb + skq * 4];
        __syncthreads();
        As[skq * 4 + 0][srow] = a4.x; As[skq * 4 + 1][srow] = a4.y;
        As[skq * 4 + 2][srow] = a4.z; As[skq * 4 + 3][srow] = a4.w;
        Bs[skq * 4 + 0][srow] = b4.x; Bs[skq * 4 + 1][srow] = b4.y;
        Bs[skq * 4 + 2][srow] = b4.z; Bs[skq * 4 + 3][srow] = b4.w;
        __syncthreads();
#pragma unroll
        for (int k = 0; k < 16; ++k) {
            float4 av = *(const float4*)&As[k][tr * 4];
            float4 bv = *(const float4*)&Bs[k][tc * 4];
            float ar[4] = {av.x, av.y, av.z, av.w};
            float br[4] = {bv.x, bv.y, bv.z, bv.w};
#pragma unroll
            for (int r = 0; r < 4; ++r)
#pragma unroll
                for (int cc = 0; cc < 4; ++cc)
                    acc[r][cc] += ar[r] * br[cc];
        }
    }

    const int cm = mat ? 0 : 1;
    float* Cp = cparts + ((size_t)p * 3 + cm) * 65536;
#pragma unroll
    for (int r = 0; r < 4; ++r) {
        float4 v = {acc[r][0] * lsc, acc[r][1] * lsc, acc[r][2] * lsc, acc[r][3] * lsc};
        *(float4*)&Cp[(size_t)(i0 + tr * 4 + r) * 256 + j0 + tc * 4] = v;
    }
    if (mat == 0) {   // also write G^T for the t2v column-LSE
        __syncthreads();
#pragma unroll
        for (int r = 0; r < 4; ++r)
#pragma unroll
            for (int cc = 0; cc < 4; ++cc)
                Tb[tc * 4 + cc][tr * 4 + r] = acc[r][cc] * lsc;
        __syncthreads();
        float* Ct = cparts + ((size_t)p * 3 + 2) * 65536;
#pragma unroll
        for (int r = 0; r < 4; ++r) {
            float4 v = *(const float4*)&Tb[tr * 4 + r][tc * 4];
            *(float4*)&Ct[(size_t)(j0 + tr * 4 + r) * 256 + i0 + tc * 4] = v;
        }
    }
}

// ---------------------------------------------------------------------------
// hl_lse: 768 blocks = cm(3) x row(256). Sum 8 K-partials, block LSE,
// loss_row = lse - x[row]; weighted atomicAdd into out.
//   cm 0: local rows (w=0.4/256), cm 1: G rows = v2t, cm 2: G^T rows = t2v
// ---------------------------------------------------------------------------
__global__ __launch_bounds__(256) void hl_lse(
    const float* __restrict__ cparts, float* __restrict__ out)
{
    __shared__ float xs[256];
    __shared__ float wred[4];
    __shared__ float bcast;

    const int b   = blockIdx.x;
    const int cm  = b >> 8;
    const int row = b & 255;
    const int tid = threadIdx.x;

    float x = 0.f;
#pragma unroll
    for (int p = 0; p < 8; ++p)
        x += cparts[((size_t)p * 3 + cm) * 65536 + (size_t)row * 256 + tid];
    xs[tid] = x;

    float m = x;
#pragma unroll
    for (int off = 32; off > 0; off >>= 1)
        m = fmaxf(m, __shfl_down(m, off, 64));
    if ((tid & 63) == 0) wred[tid >> 6] = m;
    __syncthreads();
    if (tid == 0)
        bcast = fmaxf(fmaxf(wred[0], wred[1]), fmaxf(wred[2], wred[3]));
    __syncthreads();
    float M = bcast;
    float e = expf(x - M);
#pragma unroll
    for (int off = 32; off > 0; off >>= 1)
        e += __shfl_down(e, off, 64);
    if ((tid & 63) == 0) wred[tid >> 6] = e;
    __syncthreads();
    if (tid == 0) {
        float Stot = wred[0] + wred[1] + wred[2] + wred[3];
        float lse  = M + logf(Stot);
        float w    = (cm == 0) ? (0.4f / 256.0f) : (0.3f / 256.0f);
        atomicAdd(out, w * (lse - xs[row]));
    }
}

extern "C" void kernel_launch(void* const* d_in, const int* in_sizes, int n_in,
                              void* d_out, int out_size, void* d_ws, size_t ws_size,
                              hipStream_t stream)
{
    const float* vg   = (const float*)d_in[0];  // [256,768]
    const float* tg   = (const float*)d_in[1];  // [256,768]
    const float* vl   = (const float*)d_in[2];  // [256,16,768]
    const float* tl   = (const float*)d_in[3];  // [256,32,768]
    const float* temp = (const float*)d_in[4];  // [1]
    float* out = (float*)d_out;

    float* vw     = (float*)d_ws;                   // [256,768]
    float* tb     = vw + (size_t)BB * DD;           // [256,768]
    float* cparts = tb + (size_t)BB * DD;           // [8][3][256][256]

    hipMemsetAsync(out, 0, sizeof(float) * out_size, stream);
    hl_stage1<<<dim3(BB),  dim3(512), 0, stream>>>(vl, tl, temp, vw, tb);
    hl_gemm  <<<dim3(256), dim3(256), 0, stream>>>(vg, tg, vw, tb, temp, cparts);
    hl_lse   <<<dim3(768), dim3(256), 0, stream>>>(cparts, out);
}